// Round 5
// baseline (83.596 us; speedup 1.0000x reference)
//
#include <hip/hip_runtime.h>

#define D_MODEL 256
#define TX 512
#define TM 512

__device__ __forceinline__ float fexp2(float x) { return __builtin_amdgcn_exp2f(x); }
__device__ __forceinline__ float frcp(float x)  { return __builtin_amdgcn_rcpf(x); }

// Two NT-GEMMs in one launch; epilogues write exp2(2log2e * value):
//  z=0: E1 [2048][256] = exp2(c*(x · w1^T + b1))           row-major
//  z=1: E2p packed     = exp2(c*(w2 · mem^T))  at [(d>>2)*8192 + gm*4 + (d&3)]
// Grid (32, 4, 2), block 256.
__global__ __launch_bounds__(256) void gemm_exp2(
    const float* __restrict__ x,   const float* __restrict__ mem,
    const float* __restrict__ w1,  const float* __restrict__ b1,
    const float* __restrict__ w2,
    float* __restrict__ E1, float* __restrict__ E2p)
{
    const float C_SCALE = 2.8853900817779268f; // 2*log2(e)
    const float* A; const float* W;
    int r0, n0;
    if (blockIdx.z == 0) { A = x;  W = w1; r0 = blockIdx.x * 64; n0 = blockIdx.y * 64; }
    else                 { A = w2; W = mem; r0 = blockIdx.y * 64; n0 = blockIdx.x * 64; }

    __shared__ float As[16][68];
    __shared__ float Ws[16][68];
    const int tid = threadIdx.x;
    const int tx = tid & 15, ty = tid >> 4;
    const int rl = tid >> 2, g = tid & 3;
    float acc[4][4] = {};
    const float* Ap = A + (size_t)(r0 + rl) * 256 + g * 4;
    const float* Wp = W + (size_t)(n0 + rl) * 256 + g * 4;
    for (int k0 = 0; k0 < 256; k0 += 16) {
        float4 a4 = *(const float4*)(Ap + k0);
        float4 w4 = *(const float4*)(Wp + k0);
        __syncthreads();
        As[g*4+0][rl] = a4.x; As[g*4+1][rl] = a4.y;
        As[g*4+2][rl] = a4.z; As[g*4+3][rl] = a4.w;
        Ws[g*4+0][rl] = w4.x; Ws[g*4+1][rl] = w4.y;
        Ws[g*4+2][rl] = w4.z; Ws[g*4+3][rl] = w4.w;
        __syncthreads();
        #pragma unroll
        for (int kk = 0; kk < 16; ++kk) {
            float4 av = *(const float4*)&As[kk][ty*4];
            float4 wv = *(const float4*)&Ws[kk][tx*4];
            float a_[4] = {av.x, av.y, av.z, av.w};
            float w_[4] = {wv.x, wv.y, wv.z, wv.w};
            #pragma unroll
            for (int i = 0; i < 4; ++i)
                #pragma unroll
                for (int j = 0; j < 4; ++j)
                    acc[i][j] = fmaf(a_[i], w_[j], acc[i][j]);
        }
    }
    if (blockIdx.z == 0) {
        #pragma unroll
        for (int i = 0; i < 4; ++i) {
            const int r = r0 + ty*4 + i;
            #pragma unroll
            for (int j = 0; j < 4; ++j) {
                const int n = n0 + tx*4 + j;
                E1[(size_t)r*256 + n] = fexp2(C_SCALE * (acc[i][j] + b1[n]));
            }
        }
    } else {
        #pragma unroll
        for (int i = 0; i < 4; ++i) {
            const int r = r0 + ty*4 + i;   // d index
            #pragma unroll
            for (int j = 0; j < 4; ++j) {
                const int n = n0 + tx*4 + j;  // gm index
                E2p[(size_t)(r >> 2)*8192 + (size_t)n*4 + (r & 3)] = fexp2(C_SCALE * acc[i][j]);
            }
        }
    }
}

// Fused: S = Wsum - 2*sum_d w[d]*rcp(1 + E1*E2), mask, softmax, PV.
// Grid 1024 (= B*TX/2), block 512 (8 waves). Block owns 2 x-rows; thread t owns m = t.
__global__ __launch_bounds__(512) void fused_tanh_attn(
    const float* __restrict__ E1,     // [B*TX, D]
    const float* __restrict__ E2p,    // packed [(d>>2)][gm][4]
    const float* __restrict__ memory, // [B, TM, D]
    const int*   __restrict__ mask,   // [B, TM]
    const float* __restrict__ wst,    // [D]
    float* __restrict__ out,          // [B*TX, D]
    float* __restrict__ Sout)         // [B*TX, TM]
{
    const float LOG2E = 1.4426950408889634f;
    const int t = threadIdx.x;
    const int blk = blockIdx.x;
    const int b = blk >> 8;                // 256 blocks per batch
    const int x0 = (blk & 255) * 2;
    const int wave = t >> 6, lane = t & 63;

    __shared__ float i1R[2][D_MODEL];       // 2 KB (row-major E1 rows)
    __shared__ float wsh[D_MODEL];          // 1 KB
    __shared__ float P[2][TM];              // 4 KB
    __shared__ float mneg[TM];              // 2 KB
    __shared__ float opart[2][4][D_MODEL];  // 8 KB
    __shared__ float wpart[8];

    // stage E1 rows (row-major), wst, mask
    {
        const float* i1g = E1 + ((size_t)b * TX + x0) * D_MODEL;
        const int row = t >> 8, col = t & 255;
        i1R[row][col] = i1g[(size_t)row * D_MODEL + col];
    }
    if (t < 256) wsh[t] = wst[t];
    mneg[t] = mask[b*TM + t] ? 0.f : -__builtin_inff();

    // Wsum = sum(wst)
    {
        float s = (t < 256) ? wst[t] : 0.f;
        #pragma unroll
        for (int off = 32; off > 0; off >>= 1) s += __shfl_xor(s, off);
        if (lane == 0) wpart[wave] = s;
    }

    // first E2 group load
    const float* e2ptr = E2p + ((size_t)b * TM + t) * 4;
    float4 e2 = *(const float4*)e2ptr;

    __syncthreads();
    const float Wsum = wpart[0] + wpart[1] + wpart[2] + wpart[3]
                     + wpart[4] + wpart[5] + wpart[6] + wpart[7];

    // main loop: 64 groups of 4 d; 1-deep prefetch
    float acc0 = 0.f, acc1 = 0.f;
    #pragma unroll 2
    for (int gg = 0; gg < 64; ++gg) {
        float4 e2n = e2;
        if (gg < 63) e2n = *(const float4*)(e2ptr + (size_t)(gg + 1) * 8192);
        float4 a0 = *(const float4*)&i1R[0][gg * 4];
        float4 a1 = *(const float4*)&i1R[1][gg * 4];
        float4 w4 = *(const float4*)&wsh[gg * 4];
        acc0 = fmaf(w4.x, frcp(fmaf(a0.x, e2.x, 1.f)), acc0);
        acc0 = fmaf(w4.y, frcp(fmaf(a0.y, e2.y, 1.f)), acc0);
        acc0 = fmaf(w4.z, frcp(fmaf(a0.z, e2.z, 1.f)), acc0);
        acc0 = fmaf(w4.w, frcp(fmaf(a0.w, e2.w, 1.f)), acc0);
        acc1 = fmaf(w4.x, frcp(fmaf(a1.x, e2.x, 1.f)), acc1);
        acc1 = fmaf(w4.y, frcp(fmaf(a1.y, e2.y, 1.f)), acc1);
        acc1 = fmaf(w4.z, frcp(fmaf(a1.z, e2.z, 1.f)), acc1);
        acc1 = fmaf(w4.w, frcp(fmaf(a1.w, e2.w, 1.f)), acc1);
        e2 = e2n;
    }

    // scores with mask
    {
        const float mn = mneg[t];
        P[0][t] = Wsum - 2.f * acc0 + mn;
        P[1][t] = Wsum - 2.f * acc1 + mn;
    }
    __syncthreads();

    // softmax: wave 0 -> row 0, wave 1 -> row 1 (8 values per lane)
    if (wave < 2) {
        const int xx = wave;
        float4 u0 = *(const float4*)&P[xx][lane * 8];
        float4 u1 = *(const float4*)&P[xx][lane * 8 + 4];
        float v[8] = {u0.x,u0.y,u0.z,u0.w,u1.x,u1.y,u1.z,u1.w};
        float mx = v[0];
        #pragma unroll
        for (int q = 1; q < 8; ++q) mx = fmaxf(mx, v[q]);
        #pragma unroll
        for (int off = 32; off > 0; off >>= 1) mx = fmaxf(mx, __shfl_xor(mx, off));
        float e[8];
        float sum = 0.f;
        #pragma unroll
        for (int q = 0; q < 8; ++q) { e[q] = fexp2((v[q] - mx) * LOG2E); sum += e[q]; }
        #pragma unroll
        for (int off = 32; off > 0; off >>= 1) sum += __shfl_xor(sum, off);
        const float inv = frcp(sum);
        float4 p0 = {e[0]*inv, e[1]*inv, e[2]*inv, e[3]*inv};
        float4 p1 = {e[4]*inv, e[5]*inv, e[6]*inv, e[7]*inv};
        *(float4*)&P[xx][lane*8]   = p0;
        *(float4*)&P[xx][lane*8+4] = p1;
        float* Sg = Sout + ((size_t)b*TX + x0 + xx) * TM + lane*8;
        *(float4*)Sg     = p0;
        *(float4*)(Sg+4) = p1;
    }
    __syncthreads();

    // PV: wave w -> row (w&1), m-quarter (w>>1); lane covers d = 4*lane..4*lane+3
    {
        const int row = wave & 1;
        const int q   = wave >> 1;
        const int m0  = q * 128;
        const float* mem = memory + (size_t)b * TM * D_MODEL + (size_t)m0 * D_MODEL + lane * 4;
        float4 o = {0.f, 0.f, 0.f, 0.f};
        #pragma unroll 4
        for (int m = 0; m < 128; ++m) {
            const float p = P[row][m0 + m];
            float4 mv = *(const float4*)(mem + (size_t)m * D_MODEL);
            o.x = fmaf(p, mv.x, o.x);
            o.y = fmaf(p, mv.y, o.y);
            o.z = fmaf(p, mv.z, o.z);
            o.w = fmaf(p, mv.w, o.w);
        }
        *(float4*)&opart[row][q][lane * 4] = o;
    }
    __syncthreads();

    // combine quarters: 512 outputs, 1 per thread
    {
        const int row = t >> 8;
        const int d0  = t & 255;
        float o = opart[row][0][d0] + opart[row][1][d0]
                + opart[row][2][d0] + opart[row][3][d0];
        out[((size_t)b*TX + x0 + row) * D_MODEL + d0] = o;
    }
}

extern "C" void kernel_launch(void* const* d_in, const int* in_sizes, int n_in,
                              void* d_out, int out_size, void* d_ws, size_t ws_size,
                              hipStream_t stream) {
    const float* x    = (const float*)d_in[0];
    const float* mem  = (const float*)d_in[1];
    const int*   mask = (const int*)d_in[2];
    const float* w1   = (const float*)d_in[3];
    const float* b1   = (const float*)d_in[4];
    const float* w2   = (const float*)d_in[5];
    const float* wst  = (const float*)d_in[6];

    float* out  = (float*)d_out;                  // [4*512*256]
    float* Sout = out + 4 * 512 * 256;            // [4*512*512]
    float* E1   = (float*)d_ws;                   // 524288 floats (2 MB), [2048][256]
    float* E2p  = E1 + 4 * 512 * 256;             // 524288 floats (2 MB), packed

    dim3 gg(32, 4, 2);
    gemm_exp2<<<gg, 256, 0, stream>>>(x, mem, w1, b1, w2, E1, E2p);
    fused_tanh_attn<<<1024, 512, 0, stream>>>(E1, E2p, mem, mask, wst, out, Sout);
}

// Round 6
// 73.029 us; speedup vs baseline: 1.1447x; 1.1447x over previous
//
#include <hip/hip_runtime.h>

#define D_MODEL 256
#define TX 512
#define TM 512

typedef float  v2f __attribute__((ext_vector_type(2)));
typedef unsigned int v2u __attribute__((ext_vector_type(2)));

__device__ __forceinline__ float fexp2(float x) { return __builtin_amdgcn_exp2f(x); }
__device__ __forceinline__ float frcp(float x)  { return __builtin_amdgcn_rcpf(x); }
__device__ __forceinline__ v2f pkfma(v2f a, v2f b, v2f c) { return __builtin_elementwise_fma(a, b, c); }

// Two NT-GEMMs in one launch; epilogues write exp2(2log2e * value):
//  z=0: E1 [2048][256] = exp2(c*(x · w1^T + b1))           row-major
//  z=1: E2p packed     = exp2(c*(w2 · mem^T))  at [(d>>2)*8192 + gm*4 + (d&3)]
// Grid (32, 4, 2), block 256.
__global__ __launch_bounds__(256) void gemm_exp2(
    const float* __restrict__ x,   const float* __restrict__ mem,
    const float* __restrict__ w1,  const float* __restrict__ b1,
    const float* __restrict__ w2,
    float* __restrict__ E1, float* __restrict__ E2p)
{
    const float C_SCALE = 2.8853900817779268f; // 2*log2(e)
    const float* A; const float* W;
    int r0, n0;
    if (blockIdx.z == 0) { A = x;  W = w1; r0 = blockIdx.x * 64; n0 = blockIdx.y * 64; }
    else                 { A = w2; W = mem; r0 = blockIdx.y * 64; n0 = blockIdx.x * 64; }

    __shared__ float As[16][68];
    __shared__ float Ws[16][68];
    const int tid = threadIdx.x;
    const int tx = tid & 15, ty = tid >> 4;
    const int rl = tid >> 2, g = tid & 3;
    float acc[4][4] = {};
    const float* Ap = A + (size_t)(r0 + rl) * 256 + g * 4;
    const float* Wp = W + (size_t)(n0 + rl) * 256 + g * 4;
    for (int k0 = 0; k0 < 256; k0 += 16) {
        float4 a4 = *(const float4*)(Ap + k0);
        float4 w4 = *(const float4*)(Wp + k0);
        __syncthreads();
        As[g*4+0][rl] = a4.x; As[g*4+1][rl] = a4.y;
        As[g*4+2][rl] = a4.z; As[g*4+3][rl] = a4.w;
        Ws[g*4+0][rl] = w4.x; Ws[g*4+1][rl] = w4.y;
        Ws[g*4+2][rl] = w4.z; Ws[g*4+3][rl] = w4.w;
        __syncthreads();
        #pragma unroll
        for (int kk = 0; kk < 16; ++kk) {
            float4 av = *(const float4*)&As[kk][ty*4];
            float4 wv = *(const float4*)&Ws[kk][tx*4];
            float a_[4] = {av.x, av.y, av.z, av.w};
            float w_[4] = {wv.x, wv.y, wv.z, wv.w};
            #pragma unroll
            for (int i = 0; i < 4; ++i)
                #pragma unroll
                for (int j = 0; j < 4; ++j)
                    acc[i][j] = fmaf(a_[i], w_[j], acc[i][j]);
        }
    }
    if (blockIdx.z == 0) {
        #pragma unroll
        for (int i = 0; i < 4; ++i) {
            const int r = r0 + ty*4 + i;
            #pragma unroll
            for (int j = 0; j < 4; ++j) {
                const int n = n0 + tx*4 + j;
                E1[(size_t)r*256 + n] = fexp2(C_SCALE * (acc[i][j] + b1[n]));
            }
        }
    } else {
        #pragma unroll
        for (int i = 0; i < 4; ++i) {
            const int r = r0 + ty*4 + i;   // d index
            #pragma unroll
            for (int j = 0; j < 4; ++j) {
                const int n = n0 + tx*4 + j;  // gm index
                E2p[(size_t)(r >> 2)*8192 + (size_t)n*4 + (r & 3)] = fexp2(C_SCALE * acc[i][j]);
            }
        }
    }
}

// Fused: S = Wsum - 2*sum_d w[d]/(1+E1*E2) via magic+Newton rcp (no trans),
// mask, softmax, single-pass PV (memory read once per block).
// Grid 512 (= B*TX/4), block 512 (8 waves). Block owns 4 x-rows; thread t owns m = t.
__global__ __launch_bounds__(512) void fused_tanh_attn(
    const float* __restrict__ E1,     // [B*TX, D]
    const float* __restrict__ E2p,    // packed [(d>>2)][gm][4]
    const float* __restrict__ memory, // [B, TM, D]
    const int*   __restrict__ mask,   // [B, TM]
    const float* __restrict__ wst,    // [D]
    float* __restrict__ out,          // [B*TX, D]
    float* __restrict__ Sout)         // [B*TX, TM]
{
    const float LOG2E = 1.4426950408889634f;
    const int t = threadIdx.x;
    // XCD-aware swizzle (512 = 8*64, bijective): keep a batch's blocks on 2 XCDs
    const int blk = (int)((blockIdx.x & 7) * 64 + (blockIdx.x >> 3));
    const int b = blk >> 7;                // 128 blocks per batch
    const int x0 = (blk & 127) * 4;
    const int wave = t >> 6, lane = t & 63;

    __shared__ float i1R[4][D_MODEL];       // 4 KB (row-major E1 rows)
    __shared__ float wsh[D_MODEL];          // 1 KB
    __shared__ float P[4][TM];              // 8 KB
    __shared__ float mneg[TM];              // 2 KB
    __shared__ float opart[8][4][D_MODEL];  // 32 KB (per-wave PV partials)
    __shared__ float wpart[8];

    // stage E1 rows (row-major), wst, mask
    {
        const float* i1g = E1 + ((size_t)b * TX + x0) * D_MODEL;
        #pragma unroll
        for (int k = 0; k < 2; ++k) {
            const int idx = t + k * 512;
            const int row = idx >> 8, col = idx & 255;
            i1R[row][col] = i1g[(size_t)row * D_MODEL + col];
        }
    }
    if (t < 256) wsh[t] = wst[t];
    mneg[t] = mask[b*TM + t] ? 0.f : -__builtin_inff();

    // Wsum = sum(wst)
    {
        float s = (t < 256) ? wst[t] : 0.f;
        #pragma unroll
        for (int off = 32; off > 0; off >>= 1) s += __shfl_xor(s, off);
        if (lane == 0) wpart[wave] = s;
    }

    // first E2 group load
    const float* e2ptr = E2p + ((size_t)b * TM + t) * 4;
    float4 e2 = *(const float4*)e2ptr;

    __syncthreads();
    const float Wsum = wpart[0] + wpart[1] + wpart[2] + wpart[3]
                     + wpart[4] + wpart[5] + wpart[6] + wpart[7];

    const v2f ONE  = {1.f, 1.f};
    const v2f MONE = {-1.f, -1.f};
    const v2f TWO  = {2.f, 2.f};
    const v2u MAGIC = {0x7EF311C3u, 0x7EF311C3u};

    // main loop: 64 groups of 4 d; 1-deep prefetch; magic+2-Newton reciprocal
    v2f acc01[4] = {{0,0},{0,0},{0,0},{0,0}};
    v2f acc23[4] = {{0,0},{0,0},{0,0},{0,0}};
    #pragma unroll 2
    for (int gg = 0; gg < 64; ++gg) {
        float4 e2n = e2;
        if (gg < 63) e2n = *(const float4*)(e2ptr + (size_t)(gg + 1) * 8192);
        v2f E01 = {e2.x, e2.y}, E23 = {e2.z, e2.w};
        v2f nE01 = -E01, nE23 = -E23;
        float4 wq = *(const float4*)&wsh[gg * 4];
        v2f W01 = {wq.x, wq.y}, W23 = {wq.z, wq.w};
        #pragma unroll
        for (int r = 0; r < 4; ++r) {
            float4 a = *(const float4*)&i1R[r][gg * 4];
            v2f A01 = {a.x, a.y}, A23 = {a.z, a.w};
            v2f z01  = pkfma(A01, E01, ONE);    // 1 + E1*E2  (>= 1)
            v2f z23  = pkfma(A23, E23, ONE);
            v2f zb01 = pkfma(A01, nE01, MONE);  // -(1 + E1*E2)
            v2f zb23 = pkfma(A23, nE23, MONE);
            v2f y01 = __builtin_bit_cast(v2f, MAGIC - __builtin_bit_cast(v2u, z01));
            v2f y23 = __builtin_bit_cast(v2f, MAGIC - __builtin_bit_cast(v2u, z23));
            y01 = y01 * pkfma(zb01, y01, TWO);  // Newton 1
            y23 = y23 * pkfma(zb23, y23, TWO);
            y01 = y01 * pkfma(zb01, y01, TWO);  // Newton 2
            y23 = y23 * pkfma(zb23, y23, TWO);
            acc01[r] = pkfma(W01, y01, acc01[r]);
            acc23[r] = pkfma(W23, y23, acc23[r]);
        }
        e2 = e2n;
    }

    // scores with mask
    {
        const float mn = mneg[t];
        #pragma unroll
        for (int r = 0; r < 4; ++r) {
            float s = acc01[r].x + acc01[r].y + acc23[r].x + acc23[r].y;
            P[r][t] = Wsum - 2.f * s + mn;
        }
    }
    __syncthreads();

    // softmax: waves 0..3 -> rows 0..3 (8 values per lane)
    if (wave < 4) {
        const int xx = wave;
        float4 u0 = *(const float4*)&P[xx][lane * 8];
        float4 u1 = *(const float4*)&P[xx][lane * 8 + 4];
        float v[8] = {u0.x,u0.y,u0.z,u0.w,u1.x,u1.y,u1.z,u1.w};
        float mx = v[0];
        #pragma unroll
        for (int q = 1; q < 8; ++q) mx = fmaxf(mx, v[q]);
        #pragma unroll
        for (int off = 32; off > 0; off >>= 1) mx = fmaxf(mx, __shfl_xor(mx, off));
        float e[8];
        float sum = 0.f;
        #pragma unroll
        for (int q = 0; q < 8; ++q) { e[q] = fexp2((v[q] - mx) * LOG2E); sum += e[q]; }
        #pragma unroll
        for (int off = 32; off > 0; off >>= 1) sum += __shfl_xor(sum, off);
        const float inv = frcp(sum);
        float4 p0 = {e[0]*inv, e[1]*inv, e[2]*inv, e[3]*inv};
        float4 p1 = {e[4]*inv, e[5]*inv, e[6]*inv, e[7]*inv};
        *(float4*)&P[xx][lane*8]   = p0;
        *(float4*)&P[xx][lane*8+4] = p1;
        float* Sg = Sout + ((size_t)b*TX + x0 + xx) * TM + lane*8;
        *(float4*)Sg     = p0;
        *(float4*)(Sg+4) = p1;
    }
    __syncthreads();

    // PV single-pass: wave w owns m in [w*64, w*64+64); lane owns d = 4*lane..+3.
    // Each memory element is read exactly once per block.
    {
        const int m0 = wave * 64;
        const float* memp = memory + (size_t)b * TM * D_MODEL + (size_t)m0 * D_MODEL + lane * 4;
        float4 o0 = {0,0,0,0}, o1 = {0,0,0,0}, o2 = {0,0,0,0}, o3 = {0,0,0,0};
        #pragma unroll 4
        for (int mm = 0; mm < 64; ++mm) {
            float4 mv = *(const float4*)(memp + (size_t)mm * D_MODEL);
            const float p0 = P[0][m0 + mm];
            const float p1 = P[1][m0 + mm];
            const float p2 = P[2][m0 + mm];
            const float p3 = P[3][m0 + mm];
            o0.x = fmaf(p0, mv.x, o0.x); o0.y = fmaf(p0, mv.y, o0.y);
            o0.z = fmaf(p0, mv.z, o0.z); o0.w = fmaf(p0, mv.w, o0.w);
            o1.x = fmaf(p1, mv.x, o1.x); o1.y = fmaf(p1, mv.y, o1.y);
            o1.z = fmaf(p1, mv.z, o1.z); o1.w = fmaf(p1, mv.w, o1.w);
            o2.x = fmaf(p2, mv.x, o2.x); o2.y = fmaf(p2, mv.y, o2.y);
            o2.z = fmaf(p2, mv.z, o2.z); o2.w = fmaf(p2, mv.w, o2.w);
            o3.x = fmaf(p3, mv.x, o3.x); o3.y = fmaf(p3, mv.y, o3.y);
            o3.z = fmaf(p3, mv.z, o3.z); o3.w = fmaf(p3, mv.w, o3.w);
        }
        *(float4*)&opart[wave][0][lane*4] = o0;
        *(float4*)&opart[wave][1][lane*4] = o1;
        *(float4*)&opart[wave][2][lane*4] = o2;
        *(float4*)&opart[wave][3][lane*4] = o3;
    }
    __syncthreads();

    // combine 8 wave-partials: 1024 outputs, 2 per thread
    {
        #pragma unroll
        for (int k = 0; k < 2; ++k) {
            const int idx = t + k * 512;
            const int row = idx >> 8, d0 = idx & 255;
            float s = 0.f;
            #pragma unroll
            for (int w = 0; w < 8; ++w) s += opart[w][row][d0];
            out[((size_t)b*TX + x0 + row) * D_MODEL + d0] = s;
        }
    }
}

extern "C" void kernel_launch(void* const* d_in, const int* in_sizes, int n_in,
                              void* d_out, int out_size, void* d_ws, size_t ws_size,
                              hipStream_t stream) {
    const float* x    = (const float*)d_in[0];
    const float* mem  = (const float*)d_in[1];
    const int*   mask = (const int*)d_in[2];
    const float* w1   = (const float*)d_in[3];
    const float* b1   = (const float*)d_in[4];
    const float* w2   = (const float*)d_in[5];
    const float* wst  = (const float*)d_in[6];

    float* out  = (float*)d_out;                  // [4*512*256]
    float* Sout = out + 4 * 512 * 256;            // [4*512*512]
    float* E1   = (float*)d_ws;                   // 524288 floats (2 MB), [2048][256]
    float* E2p  = E1 + 4 * 512 * 256;             // 524288 floats (2 MB), packed

    dim3 gg(32, 4, 2);
    gemm_exp2<<<gg, 256, 0, stream>>>(x, mem, w1, b1, w2, E1, E2p);
    fused_tanh_attn<<<512, 512, 0, stream>>>(E1, E2p, mem, mask, wst, out, Sout);
}